// Round 7
// baseline (244.589 us; speedup 1.0000x reference)
//
#include <hip/hip_runtime.h>

#define T_LEN 800
#define B_SZ  16
#define D_IN  80
#define CCH   256
#define OUT_CH 222
#define HOPSZ 256
#define WINSZ 512
#define NFFT  1024
#define ZLEN  (T_LEN*HOPSZ)   // 204800
#define CSTRIDE 256           // padded ccep row stride

#define PHI(i) ((i) + ((i)>>3))   // pad 1 per 8 complex: conflict-free strides

__device__ __forceinline__ float2 cmul(float2 a, float2 b){
    return make_float2(a.x*b.x - a.y*b.y, a.x*b.y + a.y*b.x);
}

// -------- weight transpose into float4 [ci][co] = (w0,w1,w2,0) --------
__global__ __launch_bounds__(256) void k_wtrans(const float* __restrict__ W1,
                                                const float* __restrict__ W2,
                                                const float* __restrict__ W3,
                                                const float* __restrict__ W4,
                                                float4* __restrict__ w1t,
                                                float4* __restrict__ w2t,
                                                float4* __restrict__ w3t,
                                                float4* __restrict__ w4t){
    const int i = blockIdx.x*256 + threadIdx.x;
    switch (blockIdx.y){
    case 0: if (i < 80*256){
        int ci = i >> 8, co = i & 255;
        const float* s = &W1[(co*80 + ci)*3];
        w1t[i] = make_float4(s[0], s[1], s[2], 0.f);
    } break;
    case 1: if (i < 32*256){
        int cil = i >> 8, co = i & 255;
        const float* s = &W2[(co*32 + cil)*3];
        w2t[i] = make_float4(s[0], s[1], s[2], 0.f);
    } break;
    case 2: if (i < 32*256){
        int cil = i >> 8, co = i & 255;
        const float* s = &W3[(co*32 + cil)*3];
        w3t[i] = make_float4(s[0], s[1], s[2], 0.f);
    } break;
    default: if (i < 256*256){
        int ci = i >> 8, co = i & 255;
        if (co < OUT_CH){
            const float* s = &W4[(co*256 + ci)*3];
            w4t[i] = make_float4(s[0], s[1], s[2], 0.f);
        } else {
            w4t[i] = make_float4(0.f, 0.f, 0.f, 0.f);
        }
    } break;
    }
}

// -------- conv1: wave owns co-slice (co=w*64+lane), thread does full t16 --------
__global__ __launch_bounds__(256) void k_conv1(const float* __restrict__ x,
                                               const float4* __restrict__ Wt,
                                               const float* __restrict__ bias,
                                               float* __restrict__ out){
    __shared__ __align__(16) float xs[80*20];
    const int t0 = blockIdx.x * 16;
    const int b  = blockIdx.y;
    const int tid = threadIdx.x;
    const int co = tid;   // (tid>>6)*64 + (tid&63)
    for (int i = tid; i < 80*18; i += 256){
        int tt = i / 80, ci = i - tt*80;
        int t = t0 - 1 + tt;
        xs[ci*20 + tt] = (t >= 0 && t < T_LEN) ? x[(b*T_LEN + t)*D_IN + ci] : 0.f;
    }
    __syncthreads();
    float acc[16];
    float bv = bias[co];
    #pragma unroll
    for (int t = 0; t < 16; ++t) acc[t] = bv;
    const float4* wp = Wt + co;
    float4 w = *wp;
    for (int ci = 0; ci < 80; ++ci){
        wp += 256;
        float4 wn = *wp;   // prefetch; overrun lands in adjacent weight buffer, unused
        const float* xp = &xs[ci*20];
        float4 v0 = *(const float4*)(xp);
        float4 v1 = *(const float4*)(xp + 4);
        float4 v2 = *(const float4*)(xp + 8);
        float4 v3 = *(const float4*)(xp + 12);
        float2 v4 = *(const float2*)(xp + 16);
        float xr[18] = {v0.x,v0.y,v0.z,v0.w, v1.x,v1.y,v1.z,v1.w,
                        v2.x,v2.y,v2.z,v2.w, v3.x,v3.y,v3.z,v3.w, v4.x,v4.y};
        #pragma unroll
        for (int t = 0; t < 16; ++t){
            acc[t] = fmaf(xr[t],   w.x, acc[t]);
            acc[t] = fmaf(xr[t+1], w.y, acc[t]);
            acc[t] = fmaf(xr[t+2], w.z, acc[t]);
        }
        w = wn;
    }
    #pragma unroll
    for (int t = 0; t < 16; ++t)
        out[(b*T_LEN + t0 + t)*CCH + co] = fmaxf(acc[t], 0.f);
}

// -------- grouped conv: wave co-slice, full t16/thread; half-wave group broadcast --------
__global__ __launch_bounds__(256) void k_convg(const float* __restrict__ in,
                                               const float4* __restrict__ Wt,
                                               const float* __restrict__ bias,
                                               float* __restrict__ out){
    __shared__ __align__(16) float hs[256*20];
    const int t0 = blockIdx.x * 16;
    const int b  = blockIdx.y;
    const int tid = threadIdx.x;
    const int co = tid;
    const int gbase = (co >> 5) << 5;   // group ci base
    for (int i = tid; i < 256*18; i += 256){
        int tt = i >> 8, ci = i & 255;
        int t = t0 - 1 + tt;
        hs[ci*20 + tt] = (t >= 0 && t < T_LEN) ? in[(b*T_LEN + t)*CCH + ci] : 0.f;
    }
    __syncthreads();
    float acc[16];
    float bv = bias[co];
    #pragma unroll
    for (int t = 0; t < 16; ++t) acc[t] = bv;
    const float4* wp = Wt + co;
    float4 w = *wp;
    for (int cil = 0; cil < 32; ++cil){
        wp += 256;
        float4 wn = *wp;
        const float* xp = &hs[(gbase + cil)*20];
        float4 v0 = *(const float4*)(xp);
        float4 v1 = *(const float4*)(xp + 4);
        float4 v2 = *(const float4*)(xp + 8);
        float4 v3 = *(const float4*)(xp + 12);
        float2 v4 = *(const float2*)(xp + 16);
        float xr[18] = {v0.x,v0.y,v0.z,v0.w, v1.x,v1.y,v1.z,v1.w,
                        v2.x,v2.y,v2.z,v2.w, v3.x,v3.y,v3.z,v3.w, v4.x,v4.y};
        #pragma unroll
        for (int t = 0; t < 16; ++t){
            acc[t] = fmaf(xr[t],   w.x, acc[t]);
            acc[t] = fmaf(xr[t+1], w.y, acc[t]);
            acc[t] = fmaf(xr[t+2], w.z, acc[t]);
        }
        w = wn;
    }
    #pragma unroll
    for (int t = 0; t < 16; ++t)
        out[(b*T_LEN + t0 + t)*CCH + co] = fmaxf(acc[t], 0.f);
}

// -------- conv4 (256->256 padded) + /quef; wave co-slice, full t16/thread --------
__global__ __launch_bounds__(256) void k_conv4(const float* __restrict__ in,
                                               const float4* __restrict__ Wt,
                                               const float* __restrict__ bias,
                                               float* __restrict__ ccep){
    __shared__ __align__(16) float hs[256*20];
    const int t0 = blockIdx.x * 16;
    const int b  = blockIdx.y;
    const int tid = threadIdx.x;
    const int co = tid;
    for (int i = tid; i < 256*18; i += 256){
        int tt = i >> 8, ci = i & 255;
        int t = t0 - 1 + tt;
        hs[ci*20 + tt] = (t >= 0 && t < T_LEN) ? in[(b*T_LEN + t)*CCH + ci] : 0.f;
    }
    __syncthreads();
    float acc[16];
    float bv = (co < OUT_CH) ? bias[co] : 0.f;
    #pragma unroll
    for (int t = 0; t < 16; ++t) acc[t] = bv;
    const float4* wp = Wt + co;
    float4 w = *wp;
    for (int ci = 0; ci < 256; ++ci){
        wp += 256;
        float4 wn = *wp;
        const float* xp = &hs[ci*20];
        float4 v0 = *(const float4*)(xp);
        float4 v1 = *(const float4*)(xp + 4);
        float4 v2 = *(const float4*)(xp + 8);
        float4 v3 = *(const float4*)(xp + 12);
        float2 v4 = *(const float2*)(xp + 16);
        float xr[18] = {v0.x,v0.y,v0.z,v0.w, v1.x,v1.y,v1.z,v1.w,
                        v2.x,v2.y,v2.z,v2.w, v3.x,v3.y,v3.z,v3.w, v4.x,v4.y};
        #pragma unroll
        for (int t = 0; t < 16; ++t){
            acc[t] = fmaf(xr[t],   w.x, acc[t]);
            acc[t] = fmaf(xr[t+1], w.y, acc[t]);
            acc[t] = fmaf(xr[t+2], w.z, acc[t]);
        }
        w = wn;
    }
    float q = (co < 111) ? (float)(111 - co) : (float)(co - 110);
    float invq = 1.0f / q;
    #pragma unroll
    for (int t = 0; t < 16; ++t)
        ccep[(b*T_LEN + t0 + t)*CSTRIDE + co] = acc[t] * invq;
}

// -------- radix-4 Stockham stage --------
template<int Ns, bool INV>
__device__ __forceinline__ void r4stage(const float2* __restrict__ src,
                                        float2* __restrict__ dst,
                                        const float2* __restrict__ Wt,
                                        int j){
    const int jm = j & (Ns - 1);
    float2 v0 = src[PHI(j)];
    float2 v1 = src[PHI(j + 256)];
    float2 v2 = src[PHI(j + 512)];
    float2 v3 = src[PHI(j + 768)];
    if (Ns > 1){
        float2 w1 = Wt[PHI(jm * (256 / Ns))];
        if (INV) w1.y = -w1.y;
        float2 w2 = cmul(w1, w1);
        float2 w3 = cmul(w2, w1);
        v1 = cmul(v1, w1);
        v2 = cmul(v2, w2);
        v3 = cmul(v3, w3);
    }
    float2 t0 = make_float2(v0.x + v2.x, v0.y + v2.y);
    float2 t1 = make_float2(v0.x - v2.x, v0.y - v2.y);
    float2 t2 = make_float2(v1.x + v3.x, v1.y + v3.y);
    float2 t3 = make_float2(v1.x - v3.x, v1.y - v3.y);
    float2 o0 = make_float2(t0.x + t2.x, t0.y + t2.y);
    float2 o2 = make_float2(t0.x - t2.x, t0.y - t2.y);
    float2 o1, o3;
    if (!INV){
        o1 = make_float2(t1.x + t3.y, t1.y - t3.x);
        o3 = make_float2(t1.x - t3.y, t1.y + t3.x);
    } else {
        o1 = make_float2(t1.x - t3.y, t1.y + t3.x);
        o3 = make_float2(t1.x + t3.y, t1.y - t3.x);
    }
    const int base = ((j - jm) << 2) + jm;
    dst[PHI(base)]          = o0;
    dst[PHI(base + Ns)]     = o1;
    dst[PHI(base + 2*Ns)]   = o2;
    dst[PHI(base + 3*Ns)]   = o3;
}

// -------- per-(b,t): packed FFT(ccep,frame) -> G = conj(F)*H -> IFFT -> window --------
__global__ __launch_bounds__(256) void k_filter(const float* __restrict__ ccep,
                                                const float* __restrict__ z,
                                                float* __restrict__ zw){
    __shared__ __align__(16) float2 A[1152];
    __shared__ __align__(16) float2 Bb[1152];
    __shared__ __align__(16) float2 Wt[288];
    const int t = blockIdx.x;
    const int b = blockIdx.y;
    const int tid = threadIdx.x;
    const float PI2 = 6.283185307179586f;

    {
        float s, c;
        __sincosf(-PI2 * (float)tid * (1.0f/1024.0f), &s, &c);
        Wt[PHI(tid)] = make_float2(c, s);
    }
    const float* crow = &ccep[(b*T_LEN + t)*CSTRIDE];
    #pragma unroll
    for (int r = 0; r < 4; ++r){
        int i = tid + (r << 8);
        float av = (i >= 401 && i < 623) ? crow[i - 401] : 0.f;
        float fv = 0.f;
        if (i < 512){
            int zi = t*HOPSZ + i - 255;
            fv = (zi >= 0 && zi < ZLEN) ? z[b*ZLEN + zi] : 0.f;
        }
        A[PHI(i)] = make_float2(av, fv);
    }
    __syncthreads();

    r4stage<1,  false>(A,  Bb, Wt, tid); __syncthreads();
    r4stage<4,  false>(Bb, A,  Wt, tid); __syncthreads();
    r4stage<16, false>(A,  Bb, Wt, tid); __syncthreads();
    r4stage<64, false>(Bb, A,  Wt, tid); __syncthreads();
    r4stage<256,false>(A,  Bb, Wt, tid); __syncthreads();

    const float LOG2_10_DIV10 = 0.33219280948873623f;
    #pragma unroll
    for (int r = 0; r < 4; ++r){
        int i = tid + (r << 8);
        float2 P = Bb[PHI(i)];
        float2 Q = Bb[PHI((1024 - i) & 1023)];
        float Are = 0.5f * (P.x + Q.x);
        float Aim = 0.5f * (P.y - Q.y);
        float Fx  = 0.5f * (P.y + Q.y);
        float Fy  = 0.5f * (Q.x - P.x);
        float mag = exp2f(Are * LOG2_10_DIV10) * (1.0f/1024.0f);
        float s, c;
        sincosf(Aim, &s, &c);
        float Hx = mag * c, Hy = mag * s;
        A[PHI(i)] = make_float2(Fx*Hx + Fy*Hy, Fx*Hy - Fy*Hx);
    }
    __syncthreads();

    r4stage<1,  true>(A,  Bb, Wt, tid); __syncthreads();
    r4stage<4,  true>(Bb, A,  Wt, tid); __syncthreads();
    r4stage<16, true>(A,  Bb, Wt, tid); __syncthreads();
    r4stage<64, true>(Bb, A,  Wt, tid); __syncthreads();
    r4stage<256,true>(A,  Bb, Wt, tid); __syncthreads();

    float* zrow = &zw[(size_t)(b*T_LEN + t)*512];
    #pragma unroll
    for (int r = 0; r < 2; ++r){
        int n = tid + (r << 8);
        float yv = Bb[PHI(511 - n)].x;
        float wv = 0.5f * (1.0f - __cosf(PI2 * (float)n * (1.0f/512.0f)));
        zrow[n] = yv * wv;
    }
}

// -------- OLA + clip --------
__global__ __launch_bounds__(256) void k_ola(const float* __restrict__ zw,
                                             float* __restrict__ out){
    const int t = blockIdx.x;
    const int b = blockIdx.y;
    const int h = threadIdx.x;
    const int tm = (t + T_LEN - 1) % T_LEN;
    float v = zw[(size_t)(b*T_LEN + t)*512 + h]
            + zw[(size_t)(b*T_LEN + tm)*512 + 256 + h];
    v = fminf(fmaxf(v, -1.0f), 1.0f);
    out[(size_t)b*ZLEN + t*HOPSZ + h] = v;
}

extern "C" void kernel_launch(void* const* d_in, const int* in_sizes, int n_in,
                              void* d_out, int out_size, void* d_ws, size_t ws_size,
                              hipStream_t stream){
    const float* x  = (const float*)d_in[0];
    const float* z  = (const float*)d_in[1];
    const float* W1 = (const float*)d_in[2];
    const float* b1 = (const float*)d_in[3];
    const float* W2 = (const float*)d_in[4];
    const float* b2 = (const float*)d_in[5];
    const float* W3 = (const float*)d_in[6];
    const float* b3 = (const float*)d_in[7];
    const float* W4 = (const float*)d_in[8];
    const float* b4 = (const float*)d_in[9];
    float* out = (float*)d_out;
    float* ws  = (float*)d_ws;

    float* h1   = ws;                 // 3,276,800 floats
    float* h2   = ws + 3276800;       // 3,276,800 floats (ccep overlays, 12800*256)
    float* ccep = h2;
    float* zwb  = ws + 6553600;       // 6,553,600 floats
    // transposed float4 weights in the FRONT of zwb (read only by convs,
    // overwritten later by k_filter — stream-ordered, safe)
    float4* w1t = (float4*)(zwb);               // 20480 float4
    float4* w2t = (float4*)(zwb + 81920);       //  8192 float4
    float4* w3t = (float4*)(zwb + 114688);      //  8192 float4
    float4* w4t = (float4*)(zwb + 147456);      // 65536 float4 (ends @409600 floats)

    dim3 blk(256);
    dim3 gwt(256, 4);
    dim3 gconv(T_LEN/16, B_SZ);       // (50,16)
    dim3 gf(T_LEN, B_SZ);             // (800,16)

    k_wtrans<<<gwt, blk, 0, stream>>>(W1, W2, W3, W4, w1t, w2t, w3t, w4t);
    k_conv1<<<gconv, blk, 0, stream>>>(x, w1t, b1, h1);
    k_convg<<<gconv, blk, 0, stream>>>(h1, w2t, b2, h2);
    k_convg<<<gconv, blk, 0, stream>>>(h2, w3t, b3, h1);
    k_conv4<<<gconv, blk, 0, stream>>>(h1, w4t, b4, ccep);
    k_filter<<<gf, blk, 0, stream>>>(ccep, z, zwb);
    k_ola<<<gf, blk, 0, stream>>>(zwb, out);
}